// Round 15
// baseline (52.040 us; speedup 1.0000x reference)
//
#include <hip/hip_runtime.h>

#define MDIM 4096
#define NDIM 4096
#define NCOEF 768
#define ALPHA 16.0f
#define PANEL_U16 (96 * 256 * 8)   // u16 per 256-row panel

typedef __attribute__((ext_vector_type(8))) short bf16x8;
typedef __attribute__((ext_vector_type(4))) float f32x4;

__device__ __forceinline__ unsigned short f2bf(float x) {
    unsigned u = __float_as_uint(x);
    u += 0x7FFFu + ((u >> 16) & 1u);
    return (unsigned short)(u >> 16);
}

__device__ __forceinline__ void glds16(const unsigned short* src, unsigned short* dst) {
    __builtin_amdgcn_global_load_lds(
        (const __attribute__((address_space(1))) void*)src,
        (__attribute__((address_space(3))) void*)dst, 16, 0, 0);
}

// ---- kernel 1 (meta fused): materialize U,V in 256-row PANEL layout ----
__global__ __launch_bounds__(256) void fill_uv(
    const int* __restrict__ fidx, const float* __restrict__ dw,
    unsigned short* __restrict__ U, unsigned short* __restrict__ V)
{
    __shared__ int idx_s[NCOEF];
    __shared__ int dup[8];
    const int b = blockIdx.x;            // (panel*96 + kc)*2 + half
    const int half = b & 1;
    const int pk = b >> 1;               // panel*96 + kc
    const int panel = pk / 96;
    const int kc = pk - panel * 96;
    const int t = threadIdx.x;
    #pragma unroll
    for (int j = 0; j < 3; ++j) idx_s[t + (j << 8)] = fidx[t + (j << 8)];
    if (t < 8) dup[t] = 0;
    __syncthreads();
    {   // dedup (last-write-wins): 32 threads per coef scan 24 q's each
        const int ci = t >> 5;
        const int pci = (kc << 3) + ci;
        const int myidx = idx_s[pci];
        const int q0 = (t & 31) * 24;
        int found = 0;
        #pragma unroll
        for (int s = 0; s < 24; ++s) {
            const int q = q0 + s;
            found |= (q > pci) & (idx_s[q] == myidx);
        }
        if (found) dup[ci] = 1;
    }
    __syncthreads();
    const int rl = (half << 7) + (t >> 1);
    const int row = (panel << 8) + rl;
    const int p0 = (kc << 3) + ((t & 1) << 2);
    const unsigned tt = 2u * (unsigned)row + 1u;
    const float wrev = 1.0f / 16384.0f;
    const float s0 = 0.015625f;
    const float s1 = 0.022097086912079612f;
    unsigned short uo[4], vo[4];
    #pragma unroll
    for (int j = 0; j < 4; ++j) {
        const int p = p0 + j;
        const int idx = idx_s[p];
        const int r = idx >> 12;
        const int c = idx & (NDIM - 1);
        const float su = (r == 0) ? s0 : s1;
        const float sv = (dup[p - (kc << 3)] ? 0.0f : 1.0f) * ALPHA * dw[p]
                         * ((c == 0) ? s0 : s1);
        const unsigned nu = (tt * (unsigned)r) & 16383u;
        const unsigned nv = (tt * (unsigned)c) & 16383u;
        uo[j] = f2bf(su * __builtin_amdgcn_cosf((float)nu * wrev));
        vo[j] = f2bf(sv * __builtin_amdgcn_cosf((float)nv * wrev));
    }
    const size_t o = ((size_t)pk * 256 + rl) * 8 + ((t & 1) << 2);
    *(ushort4*)(U + o) = *(const ushort4*)uo;
    *(ushort4*)(V + o) = *(const ushort4*)vo;
}

// ---- kernel 2: out = W + U @ V^T  (M=N=4096, K=768) ----
// 256x256 tile, 8 waves (2x4), 4 LDS bufs of BK=32. 8-PHASE template port:
// outer iter = BK=64 (bufs 2j,2j+1), 4 phases of {ds_read quadrant | 2 glds
// stage | 2 barriers | lgkmcnt(0)+sched_barrier | setprio-wrapped 16 MFMA}.
// Counted vmcnt(4) placed ONE PHASE BEFORE each buffer's first read (p1
// guards b1, p3 guards next iter's b0); never drains in main loop. Last
// iter's counted filler = the 4 epilogue-W float4 loads. Epilogue: R10's
// proven pipelined LDS-transpose (1 syncthreads/chunk, W depth-1).
__global__ __launch_bounds__(512, 1) void gemm_kernel(
    const float* __restrict__ W,
    const unsigned short* __restrict__ U,
    const unsigned short* __restrict__ V,
    float* __restrict__ out)
{
    __shared__ unsigned short SM[65536];     // 128 KB
    unsigned short* const As = SM;           // 4 bufs x 8192 u16
    unsigned short* const Bs = SM + 32768;   // 4 bufs x 8192 u16

    const int tid = threadIdx.x;         // 0..511
    const int lane = tid & 63;
    const int wave = tid >> 6;           // 0..7

    // XCD rect swizzle: 256 blocks, 8 XCDs, 4(by) x 8(bx) rect per XCD.
    const int bid = blockIdx.x;
    const int xcd = bid & 7;
    const int local = bid >> 3;
    const int by = ((xcd >> 1) << 2) + (local >> 3);   // 0..15
    const int bx = ((xcd & 1) << 3) + (local & 7);     // 0..15
    const int wr = wave >> 2;            // 0..1
    const int wc = wave & 3;             // 0..3
    const int fr = lane & 15;
    const int fks = lane >> 4;

    const unsigned short* uPan = U + (size_t)by * PANEL_U16;
    const unsigned short* vPan = V + (size_t)bx * PANEL_U16;

    f32x4 acc[8][4] = {};
    bf16x8 aQ[4], bb[4];

    const int aO = (((fks << 8) + wr * 128 + fr) << 3);
    const int bO = (((fks << 8) + wc * 64 + fr) << 3);

    // epilogue coords
    const int bcol = (bx << 8) + (lane << 2);
    const int erowBase = (by << 8);
    float4 wpre[2][4];

#define SGA(kt, buf) do {                                                   \
        const unsigned short* uS = uPan + (size_t)(kt) * 8192;              \
        glds16(uS + ((size_t)tid << 3),        &As[(buf) * 8192 + (wave << 9)]); \
        glds16(uS + 4096 + ((size_t)tid << 3), &As[(buf) * 8192 + 4096 + (wave << 9)]); \
    } while (0)
#define SGB(kt, buf) do {                                                   \
        const unsigned short* vS = vPan + (size_t)(kt) * 8192;              \
        glds16(vS + ((size_t)tid << 3),        &Bs[(buf) * 8192 + (wave << 9)]); \
        glds16(vS + 4096 + ((size_t)tid << 3), &Bs[(buf) * 8192 + 4096 + (wave << 9)]); \
    } while (0)
#define DSA(buf, base) do {                                                 \
        _Pragma("unroll")                                                   \
        for (int f = 0; f < 4; ++f)                                         \
            aQ[f] = *(const bf16x8*)&As[(buf) * 8192 + aO + (((base) + f) << 7)]; \
    } while (0)
#define DSB(buf) do {                                                       \
        _Pragma("unroll")                                                   \
        for (int f = 0; f < 4; ++f)                                         \
            bb[f] = *(const bf16x8*)&Bs[(buf) * 8192 + bO + (f << 7)];      \
    } while (0)
#define MFMAQ(fmb) do {                                                     \
        __builtin_amdgcn_s_setprio(1);                                      \
        _Pragma("unroll")                                                   \
        for (int fm = 0; fm < 4; ++fm)                                      \
            _Pragma("unroll")                                               \
            for (int fn = 0; fn < 4; ++fn)                                  \
                acc[(fmb) + fm][fn] = __builtin_amdgcn_mfma_f32_16x16x32_bf16( \
                    bb[fn], aQ[fm], acc[(fmb) + fm][fn], 0, 0, 0);          \
        __builtin_amdgcn_s_setprio(0);                                      \
    } while (0)
#define BAR()  __builtin_amdgcn_s_barrier()
#define LGKM() do { asm volatile("s_waitcnt lgkmcnt(0)" ::: "memory");      \
                    __builtin_amdgcn_sched_barrier(0); } while (0)
#define VW4()  asm volatile("s_waitcnt vmcnt(4)" ::: "memory")

    // prologue: stage bufs 0,1; wait buf0 (counted: buf1's 4 stay in flight)
    SGA(0, 0); SGB(0, 0); SGA(1, 1); SGB(1, 1);
    VW4();
    BAR();

    #pragma unroll
    for (int j = 0; j < 12; ++j) {
        const int b0 = (2 * j) & 3, b1 = (2 * j + 1) & 3;
        const int n0 = (2 * j + 2) & 3, n1 = (2 * j + 3) & 3;
        // -- phase 0: a0-3,b0-3 of b0 | stage A(n0) | 16 MFMA fm0-3
        DSA(b0, 0); DSB(b0);
        if (j < 11) { SGA(2 * j + 2, n0); }
        else {
            wpre[0][0] = *(const float4*)(W + (size_t)(erowBase + wave * 4 + 0) * NDIM + bcol);
            wpre[0][1] = *(const float4*)(W + (size_t)(erowBase + wave * 4 + 1) * NDIM + bcol);
        }
        BAR(); LGKM(); MFMAQ(0); BAR();
        // -- phase 1: a4-7 of b0 | stage B(n0) | VW(4) guards b1 | fm4-7
        DSA(b0, 4);
        if (j < 11) { SGB(2 * j + 2, n0); }
        else {
            wpre[0][2] = *(const float4*)(W + (size_t)(erowBase + wave * 4 + 2) * NDIM + bcol);
            wpre[0][3] = *(const float4*)(W + (size_t)(erowBase + wave * 4 + 3) * NDIM + bcol);
        }
        VW4();
        BAR(); LGKM(); MFMAQ(4); BAR();
        // -- phase 2: a0-3,b0-3 of b1 | stage A(n1) | fm0-3
        DSA(b1, 0); DSB(b1);
        if (j < 11) SGA(2 * j + 3, n1);
        BAR(); LGKM(); MFMAQ(0); BAR();
        // -- phase 3: a4-7 of b1 | stage B(n1) | VW(4) guards next b0 | fm4-7
        DSA(b1, 4);
        if (j < 11) { SGB(2 * j + 3, n1); VW4(); }
        BAR(); LGKM(); MFMAQ(4); BAR();
    }

    // ---- epilogue: out = W + acc, pipelined LDS transpose (R10) ----
    // acc[fm][fn][jj] = tile[wr*128+fm*16+fr][wc*64+fn*16+fks*4+jj]
    // chunk c: rows 32c..32c+31, owner wr == c>>2, acc pair (c&3)*2.
    // Two L regions 32x258 f32 at f32 offsets 0 / 8256 (66 KB < 128 KB).
    float* const L = (float*)SM;
    if (wr == 0) {   // prologue: chunk 0 into region 0
        #pragma unroll
        for (int f2 = 0; f2 < 2; ++f2)
            #pragma unroll
            for (int fn = 0; fn < 4; ++fn)
                *(f32x4*)(L + (f2 * 16 + fr) * 258 + wc * 64 + fn * 16 + fks * 4)
                    = acc[f2][fn];
    }
    #pragma unroll
    for (int c = 0; c < 8; ++c) {
        __syncthreads();     // chunk-c L writes visible; drains vmcnt (wpre ready)
        if (c < 7) {
            #pragma unroll
            for (int i = 0; i < 4; ++i)
                wpre[(c + 1) & 1][i] = *(const float4*)(
                    W + (size_t)(erowBase + (c + 1) * 32 + wave * 4 + i) * NDIM + bcol);
            if (wr == ((c + 1) >> 2)) {
                #pragma unroll
                for (int f2 = 0; f2 < 2; ++f2)
                    #pragma unroll
                    for (int fn = 0; fn < 4; ++fn)
                        *(f32x4*)(L + ((c + 1) & 1) * 8256
                                  + (f2 * 16 + fr) * 258 + wc * 64 + fn * 16 + fks * 4)
                            = acc[((c + 1) & 3) * 2 + f2][fn];
            }
        }
        #pragma unroll
        for (int i = 0; i < 4; ++i) {
            const int rl2 = wave * 4 + i;
            const size_t o = (size_t)(erowBase + c * 32 + rl2) * NDIM + bcol;
            const f32x4 l4 = *(const f32x4*)(L + (c & 1) * 8256 + rl2 * 258 + (lane << 2));
            float4 r4;
            r4.x = wpre[c & 1][i].x + l4[0];
            r4.y = wpre[c & 1][i].y + l4[1];
            r4.z = wpre[c & 1][i].z + l4[2];
            r4.w = wpre[c & 1][i].w + l4[3];
            *(float4*)(out + o) = r4;
        }
    }
#undef SGA
#undef SGB
#undef DSA
#undef DSB
#undef MFMAQ
#undef BAR
#undef LGKM
#undef VW4
}

extern "C" void kernel_launch(void* const* d_in, const int* in_sizes, int n_in,
                              void* d_out, int out_size, void* d_ws, size_t ws_size,
                              hipStream_t stream) {
    const float* weight = (const float*)d_in[0];
    const float* dw     = (const float*)d_in[1];
    const int*   fidx   = (const int*)d_in[2];
    float* out = (float*)d_out;

    char* ws = (char*)d_ws;
    unsigned short* U = (unsigned short*)ws;                       // 6,291,456 B
    unsigned short* V = (unsigned short*)(ws + 6291456);           // 6,291,456 B

    fill_uv<<<16 * 96 * 2, 256, 0, stream>>>(fidx, dw, U, V);
    gemm_kernel<<<256, 512, 0, stream>>>(weight, U, V, out);
}